// Round 2
// baseline (1306.857 us; speedup 1.0000x reference)
//
#include <hip/hip_runtime.h>
#include <hip/hip_bf16.h>
#include <math.h>

#define NTOK 8192
#define DIM  1024
#define FFN  4096
#define NEXP 10

// pass-1 (K=DIM): BM=256, BN=256 tiles. pass-2 (K=FFN): BM=128, BN=256.
#define NX1_SH (NTOK / 256)              // 32
#define NX1_RT (NTOK / 256 + NEXP - 1)   // 41
#define NX2_SH (NTOK / 128)              // 64
#define NX2_RT (NTOK / 128 + NEXP - 1)   // 73
#define NY1 ((FFN + DIM) / 256)          // 20 (16 W1 + 4 Wg)
#define NY2 (DIM / 256)                  // 4

typedef __attribute__((ext_vector_type(8))) short bf16x8;   // 8 bf16 = 4 VGPR (MFMA A/B frag)
typedef __attribute__((ext_vector_type(4))) float f32x4;    // MFMA C/D frag

static __device__ __forceinline__ unsigned short f2bf(float f) {
  __hip_bfloat16 h = __float2bfloat16(f);
  return *reinterpret_cast<unsigned short*>(&h);
}

// async global->LDS, 16B/lane. LDS dest = wave-uniform base + lane*16.
static __device__ __forceinline__ void gld_lds16(const unsigned short* g, unsigned short* l) {
  __builtin_amdgcn_global_load_lds((const __attribute__((address_space(1))) unsigned int*)g,
                                   (__attribute__((address_space(3))) unsigned int*)l,
                                   16, 0, 0);
}

template <int N>
static __device__ __forceinline__ void waitv() {
  asm volatile("s_waitcnt vmcnt(%0)" :: "i"(N) : "memory");
}

// flat block id -> (bx, by): XCD-chunked bijective swizzle (m204), by-fastest groups of G.
template <int NX, int NY, int G>
static __device__ __forceinline__ void map_block(int orig, int& bx, int& by) {
  const int n = NX * NY;
  int xcd = orig & 7, o = orig >> 3;
  const int q = n >> 3, r = n & 7;
  int id = (xcd < r ? xcd * (q + 1) : r * (q + 1) + (xcd - r) * q) + o;
  const int gsz = NX * G;          // NY % G == 0 for all instantiations
  int grp = id / gsz;
  int rem = id - grp * gsz;
  bx = rem / G;
  by = grp * G + (rem - bx * G);
}

// ---------------- routing ----------------
__global__ void k_zero(int* cnt) { if (threadIdx.x < NEXP) cnt[threadIdx.x] = 0; }

__global__ void k_count(const int* __restrict__ dom, int* __restrict__ cnt, int* __restrict__ pos) {
  int t = blockIdx.x * 256 + threadIdx.x;
  if (t < NTOK) pos[t] = atomicAdd(&cnt[dom[t]], 1);
}

// prefix offsets + exact (expert, m-tile) work lists at 256 and 128 granularity
__global__ void k_offsets(const int* __restrict__ cnt, int* __restrict__ segoff,
                          int* __restrict__ tm256, int* __restrict__ nt256,
                          int* __restrict__ tm128, int* __restrict__ nt128) {
  if (threadIdx.x == 0) {
    int s = 0, k2 = 0, k1 = 0;
    for (int e = 0; e < NEXP; e++) {
      segoff[e] = s;
      int c = cnt[e];
      for (int t = 0; t < ((c + 255) >> 8); t++) tm256[k2++] = (e << 16) | t;
      for (int t = 0; t < ((c + 127) >> 7); t++) tm128[k1++] = (e << 16) | t;
      s += c;
    }
    segoff[NEXP] = s;
    *nt256 = k2;
    *nt128 = k1;
  }
}

__global__ void k_scatter(const int* __restrict__ dom, const int* __restrict__ pos,
                          const int* __restrict__ segoff, int* __restrict__ perm) {
  int t = blockIdx.x * 256 + threadIdx.x;
  if (t < NTOK) perm[segoff[dom[t]] + pos[t]] = t;
}

// ---------------- fp32 -> bf16 convert (row-major preserved; for x) ----------------
__global__ void k_convert(const float* __restrict__ src, unsigned short* __restrict__ dst, int n8) {
  int i = blockIdx.x * 256 + threadIdx.x;
  if (i >= n8) return;
  const float4* s = (const float4*)(src + (size_t)i * 8);
  float4 a = s[0], b = s[1];
  union { unsigned short h[8]; uint4 v; } u;
  u.h[0] = f2bf(a.x); u.h[1] = f2bf(a.y); u.h[2] = f2bf(a.z); u.h[3] = f2bf(a.w);
  u.h[4] = f2bf(b.x); u.h[5] = f2bf(b.y); u.h[6] = f2bf(b.z); u.h[7] = f2bf(b.w);
  *(uint4*)(dst + (size_t)i * 8) = u.v;
}

// gather bf16 x rows into sorted (segment) order
__global__ void k_gather(const unsigned short* __restrict__ xb, const int* __restrict__ perm,
                         unsigned short* __restrict__ xs) {
  int i = blockIdx.x * 256 + threadIdx.x;
  int row = i >> 7;
  int c = (i & 127) * 8;
  int src = perm[row];
  *(uint4*)(xs + (size_t)row * DIM + c) = *(const uint4*)(xb + (size_t)src * DIM + c);
}

// ---------------- fp32 [K][N] -> bf16 [N][K] transpose-convert (weights) ----------------
__global__ void k_transpose(const float* __restrict__ src, unsigned short* __restrict__ dst,
                            int K, int N) {
  size_t moff = (size_t)blockIdx.z * K * N;
  src += moff; dst += moff;
  __shared__ float tile[64][65];
  int n0 = blockIdx.x * 64, k0 = blockIdx.y * 64;
  int t = threadIdx.x;
  int tx = t & 15, ty = t >> 4;
#pragma unroll
  for (int i = 0; i < 4; i++) {
    int kk = ty + i * 16;
    float4 v = *(const float4*)(src + (size_t)(k0 + kk) * N + n0 + tx * 4);
    tile[kk][tx * 4 + 0] = v.x; tile[kk][tx * 4 + 1] = v.y;
    tile[kk][tx * 4 + 2] = v.z; tile[kk][tx * 4 + 3] = v.w;
  }
  __syncthreads();
#pragma unroll
  for (int i = 0; i < 2; i++) {
    int chunk = t + i * 256;
    int nl = chunk >> 3;
    int k8 = (chunk & 7) * 8;
    union { unsigned short h[8]; uint4 v; } u;
#pragma unroll
    for (int j = 0; j < 8; j++) u.h[j] = f2bf(tile[k8 + j][nl]);
    *(uint4*)(dst + (size_t)(n0 + nl) * K + k0 + k8) = u.v;
  }
}

// ---------------- deep-pipelined MFMA core ----------------
// BM x 256 tile, K staged in 32-wide slices into 4 rotating LDS slots (depth-3 prefetch).
// Counted vmcnt (never 0 in steady state); raw s_barrier; setprio around MFMA clusters.
// LDS XOR swizzle: 16B-slot ^= (row>>1)&3, applied via pre-swizzled global source
// (global_load_lds writes linearly) and on the ds_read address (lane-constant term).
// Per-slice: phase0 reads a[0..MREP/2)+b[0..4), stages next A; phase1 reads a-high, stages B.
// Safety: slot (s+3)&3 == (s-1)&3 was last read in slice s-1, whose reads complete before
// its end-barrier; stage-issues for slice s+3 occur after that barrier. waitv<2*LPS> at
// slice end completes all of slice s+1's loads (leaves s+2,s+3 in flight); the barrier
// after it publishes every wave's staging before any wave reads slice s+1.
template <int BM, int KLEN, int MREP>
__device__ __forceinline__ void gemm_pipeline(
    const unsigned short* pA0, const unsigned short* pA1,
    const unsigned short* pB0, const unsigned short* pB1,
    unsigned short* As, unsigned short* Bs, int tid,
    f32x4 acc[MREP][4])
{
  constexpr int NS    = KLEN / 32;
  constexpr int NEA   = BM / 128;      // A stage events per slice (1 or 2)
  constexpr int LPS   = NEA + 2;       // loads per slice per thread
  constexpr int ASLOT = BM * 32;       // ushorts per A slot
  constexpr int BSLOT = 256 * 32;

  const int lane = tid & 63, wid = tid >> 6;
  const int wm = wid >> 2, wn = wid & 3;
  const int m16 = lane & 15;
  const int q = lane >> 4;
  const int kslot = q ^ ((m16 >> 1) & 3);                 // swizzled 16B-slot (lane-constant)
  const int aoff = (wm * (BM / 2) + m16) * 32 + kslot * 8;
  const int boff = (wn * 64 + m16) * 32 + kslot * 8;

  // prologue: stage slices 0..2 into slots 0..2
#pragma unroll
  for (int s = 0; s < 3; ++s) {
    gld_lds16(pA0 + s * 32, As + s * ASLOT + tid * 8);
    if (NEA == 2) gld_lds16(pA1 + s * 32, As + s * ASLOT + 4096 + tid * 8);
    gld_lds16(pB0 + s * 32, Bs + s * BSLOT + tid * 8);
    gld_lds16(pB1 + s * 32, Bs + s * BSLOT + 4096 + tid * 8);
  }
  pA0 += 96; pA1 += 96; pB0 += 96; pB1 += 96;
  waitv<2 * LPS>();
  __builtin_amdgcn_s_barrier();

  auto slice = [&](int s, bool stage, auto dowait) {
    const int so = s & 3, sn = (s + 3) & 3;
    const unsigned short* Asl = As + so * ASLOT;
    const unsigned short* Bsl = Bs + so * BSLOT;
    bf16x8 b[4], a[MREP / 2];
#pragma unroll
    for (int i = 0; i < MREP / 2; ++i) a[i] = *(const bf16x8*)(Asl + aoff + i * 512);
#pragma unroll
    for (int j = 0; j < 4; ++j)        b[j] = *(const bf16x8*)(Bsl + boff + j * 512);
    if (stage) {
      gld_lds16(pA0, As + sn * ASLOT + tid * 8); pA0 += 32;
      if (NEA == 2) { gld_lds16(pA1, As + sn * ASLOT + 4096 + tid * 8); pA1 += 32; }
    }
    __builtin_amdgcn_s_barrier();
    __builtin_amdgcn_s_setprio(1);
#pragma unroll
    for (int i = 0; i < MREP / 2; ++i)
#pragma unroll
      for (int j = 0; j < 4; ++j)
        acc[i][j] = __builtin_amdgcn_mfma_f32_16x16x32_bf16(a[i], b[j], acc[i][j], 0, 0, 0);
    __builtin_amdgcn_s_setprio(0);
    // phase 1
#pragma unroll
    for (int i = 0; i < MREP / 2; ++i) a[i] = *(const bf16x8*)(Asl + aoff + (MREP / 2 + i) * 512);
    if (stage) {
      gld_lds16(pB0, Bs + sn * BSLOT + tid * 8); pB0 += 32;
      gld_lds16(pB1, Bs + sn * BSLOT + 4096 + tid * 8); pB1 += 32;
    }
    __builtin_amdgcn_s_barrier();
    __builtin_amdgcn_s_setprio(1);
#pragma unroll
    for (int i = 0; i < MREP / 2; ++i)
#pragma unroll
      for (int j = 0; j < 4; ++j)
        acc[MREP / 2 + i][j] =
            __builtin_amdgcn_mfma_f32_16x16x32_bf16(a[i], b[j], acc[MREP / 2 + i][j], 0, 0, 0);
    __builtin_amdgcn_s_setprio(0);
    dowait();
    __builtin_amdgcn_s_barrier();
  };

#pragma clang loop unroll(disable)
  for (int s = 0; s < NS - 3; ++s) slice(s, true, [] { waitv<2 * LPS>(); });
  slice(NS - 3, false, [] { waitv<LPS>(); });
  slice(NS - 2, false, [] { waitv<0>(); });
  slice(NS - 1, false, [] {});
}

// ---------------- pass 1: h1 = gelu(A@W1+b1) AND g = sigmoid(A@Wg+bg), K=DIM ----------------
template <bool ROUTED>
__global__ __launch_bounds__(512, 2)
void k_p1(const unsigned short* __restrict__ A,
          const unsigned short* __restrict__ W1t, const float* __restrict__ b1,
          const unsigned short* __restrict__ Wgt, const float* __restrict__ bg,
          unsigned short* __restrict__ h1, float* __restrict__ g,
          const int* __restrict__ segoff, const int* __restrict__ tilemap,
          const int* __restrict__ ntilesp) {
  constexpr int NXW = ROUTED ? NX1_RT : NX1_SH;
  int bx, by;
  map_block<NXW, NY1, 4>((int)blockIdx.x, bx, by);

  int e = 0, seg0 = 0, cnt = NTOK, m0;
  if (ROUTED) {
    if (bx >= *ntilesp) return;
    int tm = tilemap[bx];
    e = tm >> 16; seg0 = segoff[e]; cnt = segoff[e + 1] - seg0;
    m0 = (tm & 0xffff) << 8;
  } else {
    m0 = bx << 8;
  }
  const bool isW1 = by < (FFN / 256);
  const int n0 = (isW1 ? by : by - FFN / 256) << 8;
  const unsigned short* Bte = isW1 ? W1t + (size_t)e * FFN * DIM + (size_t)n0 * DIM
                                   : Wgt + (size_t)e * DIM * DIM + (size_t)n0 * DIM;
  const float* be = (isW1 ? b1 + (size_t)e * FFN : bg + (size_t)e * DIM) + n0;

  __shared__ unsigned short As[4 * 256 * 32];
  __shared__ unsigned short Bs[4 * 256 * 32];

  int tid = threadIdx.x;
  int r = tid >> 2;
  int kgx = (tid & 3) ^ ((tid >> 3) & 3);   // pre-swizzled source k-group

  auto arow = [&](int rl) -> size_t {
    int l = m0 + rl;
    if (ROUTED && l > cnt - 1) l = cnt - 1;   // clamp (masked at store)
    return (size_t)(seg0 + l);
  };
  const unsigned short* pA0 = A + arow(r) * DIM + kgx * 8;
  const unsigned short* pA1 = A + arow(128 + r) * DIM + kgx * 8;
  const unsigned short* pB0 = Bte + (size_t)r * DIM + kgx * 8;
  const unsigned short* pB1 = Bte + (size_t)(128 + r) * DIM + kgx * 8;

  f32x4 acc[8][4];
#pragma unroll
  for (int i = 0; i < 8; ++i)
#pragma unroll
    for (int j = 0; j < 4; ++j) acc[i][j] = (f32x4){0.f, 0.f, 0.f, 0.f};

  gemm_pipeline<256, DIM, 8>(pA0, pA1, pB0, pB1, As, Bs, tid, acc);

  // epilogue: C/D layout col = lane&15, row = (lane>>4)*4 + reg
  int lane = tid & 63, wid = tid >> 6, wm = wid >> 2, wn = wid & 3;
  int m16 = lane & 15, q = lane >> 4;
#pragma unroll
  for (int i = 0; i < 8; ++i) {
#pragma unroll
    for (int j = 0; j < 4; ++j) {
      int cn = wn * 64 + j * 16 + m16;
      int col = n0 + cn;
      float bb = be[cn];
#pragma unroll
      for (int rr = 0; rr < 4; ++rr) {
        int rl = wm * 128 + i * 16 + q * 4 + rr;
        int l = m0 + rl;
        if (ROUTED && l >= cnt) continue;
        float z = acc[i][j][rr] + bb;
        size_t row = (size_t)(seg0 + l);
        if (isW1) {
          // tanh-form gelu: |err| <= 3e-3, below bf16 h1 quantization
          float u = 0.79788456f * z * (1.0f + 0.044715f * z * z);
          float o = z / (1.0f + __expf(-2.0f * u));
          h1[row * (size_t)FFN + col] = f2bf(o);
        } else {
          g[row * (size_t)DIM + col] = 1.0f / (1.0f + __expf(-z));
        }
      }
    }
  }
}

// ---------------- pass 2: h = A@W2+b2+x; out (=/+=) g*h+(1-g)*x, K=FFN ----------------
template <bool ROUTED>
__global__ __launch_bounds__(512, 2)
void k_p2(const unsigned short* __restrict__ A,     // h1 bf16 (sorted rows if ROUTED)
          const unsigned short* __restrict__ W2t,   // bf16 [(e,) DIM, FFN]
          const float* __restrict__ b2,
          const float* __restrict__ g,
          const float* __restrict__ xres,
          float* __restrict__ out,
          const int* __restrict__ perm,
          const int* __restrict__ segoff,
          const int* __restrict__ tilemap,
          const int* __restrict__ ntilesp) {
  constexpr int NXW = ROUTED ? NX2_RT : NX2_SH;
  int bx, by;
  map_block<NXW, NY2, 2>((int)blockIdx.x, bx, by);

  int e = 0, seg0 = 0, cnt = NTOK, m0;
  if (ROUTED) {
    if (bx >= *ntilesp) return;
    int tm = tilemap[bx];
    e = tm >> 16; seg0 = segoff[e]; cnt = segoff[e + 1] - seg0;
    m0 = (tm & 0xffff) << 7;
  } else {
    m0 = bx << 7;
  }
  const int n0 = by << 8;
  const unsigned short* Bte = W2t + (size_t)e * DIM * FFN + (size_t)n0 * FFN;
  const float* be = b2 + (size_t)e * DIM + n0;

  __shared__ unsigned short As[4 * 128 * 32];
  __shared__ unsigned short Bs[4 * 256 * 32];

  int tid = threadIdx.x;
  int r = tid >> 2;
  int kgx = (tid & 3) ^ ((tid >> 3) & 3);

  auto arow = [&](int rl) -> size_t {
    int l = m0 + rl;
    if (ROUTED && l > cnt - 1) l = cnt - 1;
    return (size_t)(seg0 + l);
  };
  const unsigned short* pA0 = A + arow(r) * FFN + kgx * 8;
  const unsigned short* pB0 = Bte + (size_t)r * FFN + kgx * 8;
  const unsigned short* pB1 = Bte + (size_t)(128 + r) * FFN + kgx * 8;

  f32x4 acc[4][4];
#pragma unroll
  for (int i = 0; i < 4; ++i)
#pragma unroll
    for (int j = 0; j < 4; ++j) acc[i][j] = (f32x4){0.f, 0.f, 0.f, 0.f};

  gemm_pipeline<128, FFN, 4>(pA0, pA0, pB0, pB1, As, Bs, tid, acc);

  int lane = tid & 63, wid = tid >> 6, wm = wid >> 2, wn = wid & 3;
  int m16 = lane & 15, q = lane >> 4;
#pragma unroll
  for (int i = 0; i < 4; ++i) {
#pragma unroll
    for (int j = 0; j < 4; ++j) {
      int cn = wn * 64 + j * 16 + m16;
      int col = n0 + cn;
      float bb = be[cn];
#pragma unroll
      for (int rr = 0; rr < 4; ++rr) {
        int rl = wm * 64 + i * 16 + q * 4 + rr;
        int l = m0 + rl;
        if (ROUTED && l >= cnt) continue;
        int lidx = seg0 + l;
        int grow = ROUTED ? perm[lidx] : l;      // global token row
        float xv = xres[(size_t)grow * DIM + col];
        float gv = g[(size_t)lidx * DIM + col];
        float h = acc[i][j][rr] + bb + xv;
        float o = gv * h + (1.0f - gv) * xv;
        float* po = &out[(size_t)grow * DIM + col];
        if (ROUTED) *po += o;   // unique rows per token: no atomics needed
        else        *po = o;
      }
    }
  }
}

extern "C" void kernel_launch(void* const* d_in, const int* in_sizes, int n_in,
                              void* d_out, int out_size, void* d_ws, size_t ws_size,
                              hipStream_t stream) {
  (void)in_sizes; (void)n_in; (void)out_size; (void)ws_size;
  const float* x   = (const float*)d_in[0];
  const int*   dom = (const int*)d_in[1];
  const float* sW1 = (const float*)d_in[2];
  const float* sb1 = (const float*)d_in[3];
  const float* sW2 = (const float*)d_in[4];
  const float* sb2 = (const float*)d_in[5];
  const float* sWg = (const float*)d_in[6];
  const float* sbg = (const float*)d_in[7];
  const float* dW1 = (const float*)d_in[8];
  const float* db1 = (const float*)d_in[9];
  const float* dW2 = (const float*)d_in[10];
  const float* db2 = (const float*)d_in[11];
  const float* dWg = (const float*)d_in[12];
  const float* dbg = (const float*)d_in[13];
  float* out = (float*)d_out;

  char* p = (char*)d_ws;
  auto take = [&](size_t b) { char* r = p; p += (b + 255) & ~(size_t)255; return r; };
  int* cnt     = (int*)take(NEXP * 4);
  int* segoff  = (int*)take((NEXP + 1) * 4);
  int* tm256   = (int*)take(64 * 4);
  int* nt256   = (int*)take(4);
  int* tm128   = (int*)take(128 * 4);
  int* nt128   = (int*)take(4);
  int* pos     = (int*)take((size_t)NTOK * 4);
  int* perm    = (int*)take((size_t)NTOK * 4);
  unsigned short* xb   = (unsigned short*)take((size_t)NTOK * DIM * 2);
  unsigned short* xs   = (unsigned short*)take((size_t)NTOK * DIM * 2);   // sorted x
  unsigned short* h1   = (unsigned short*)take((size_t)NTOK * FFN * 2);   // reused shared->routed
  float*          g    = (float*)take((size_t)NTOK * DIM * 4);            // reused shared->routed
  unsigned short* sW1t = (unsigned short*)take((size_t)DIM * FFN * 2);
  unsigned short* sW2t = (unsigned short*)take((size_t)FFN * DIM * 2);
  unsigned short* sWgt = (unsigned short*)take((size_t)DIM * DIM * 2);
  unsigned short* dW1t = (unsigned short*)take((size_t)NEXP * DIM * FFN * 2);
  unsigned short* dW2t = (unsigned short*)take((size_t)NEXP * FFN * DIM * 2);
  unsigned short* dWgt = (unsigned short*)take((size_t)NEXP * DIM * DIM * 2);

  // routing (+ exact routed tile lists)
  k_zero<<<1, 64, 0, stream>>>(cnt);
  k_count<<<NTOK / 256, 256, 0, stream>>>(dom, cnt, pos);
  k_offsets<<<1, 1, 0, stream>>>(cnt, segoff, tm256, nt256, tm128, nt128);
  k_scatter<<<NTOK / 256, 256, 0, stream>>>(dom, pos, segoff, perm);

  // convert x; gather sorted x; transpose-convert all weights to bf16 [N][K]
  k_convert<<<(NTOK * DIM / 8) / 256, 256, 0, stream>>>(x, xb, NTOK * DIM / 8);
  k_gather<<<(NTOK * DIM / 8) / 256, 256, 0, stream>>>(xb, perm, xs);
  k_transpose<<<dim3(FFN / 64, DIM / 64, 1),    256, 0, stream>>>(sW1, sW1t, DIM, FFN);
  k_transpose<<<dim3(DIM / 64, FFN / 64, 1),    256, 0, stream>>>(sW2, sW2t, FFN, DIM);
  k_transpose<<<dim3(DIM / 64, DIM / 64, 1),    256, 0, stream>>>(sWg, sWgt, DIM, DIM);
  k_transpose<<<dim3(FFN / 64, DIM / 64, NEXP), 256, 0, stream>>>(dW1, dW1t, DIM, FFN);
  k_transpose<<<dim3(DIM / 64, FFN / 64, NEXP), 256, 0, stream>>>(dW2, dW2t, FFN, DIM);
  k_transpose<<<dim3(DIM / 64, DIM / 64, NEXP), 256, 0, stream>>>(dWg, dWgt, DIM, DIM);

  // shared expert pass (writes every out element)
  k_p1<false><<<NX1_SH * NY1, 512, 0, stream>>>(
      xb, sW1t, sb1, sWgt, sbg, h1, g, nullptr, nullptr, nullptr);
  k_p2<false><<<NX2_SH * NY2, 512, 0, stream>>>(
      h1, sW2t, sb2, g, x, out, nullptr, nullptr, nullptr, nullptr);

  // routed expert pass (accumulates into out); reuses h1/g at sorted rows
  k_p1<true><<<NX1_RT * NY1, 512, 0, stream>>>(
      xs, dW1t, db1, dWgt, dbg, h1, g, segoff, tm256, nt256);
  k_p2<true><<<NX2_RT * NY2, 512, 0, stream>>>(
      h1, dW2t, db2, g, x, out, perm, segoff, tm128, nt128);
}

// Round 3
// 1183.593 us; speedup vs baseline: 1.1041x; 1.1041x over previous
//
#include <hip/hip_runtime.h>
#include <hip/hip_bf16.h>
#include <math.h>

#define NTOK 8192
#define DIM  1024
#define FFN  4096
#define NEXP 10

#define NT_SH (NTOK / 128)             // 64 shared m-tiles
#define NT_RT (NTOK / 128 + NEXP - 1)  // 73 = worst-case sum of ceil(cnt_e/128)
#define NY01  ((FFN + DIM) / 128)      // 40 n-tiles: 32 for W1, 8 for Wg
#define NY2   (DIM / 128)              // 8

typedef __attribute__((ext_vector_type(8))) short bf16x8;   // 8 bf16 = 4 VGPR (MFMA A/B frag)
typedef __attribute__((ext_vector_type(4))) float f32x4;    // MFMA C/D frag

static __device__ __forceinline__ unsigned short f2bf(float f) {
  __hip_bfloat16 h = __float2bfloat16(f);
  return *reinterpret_cast<unsigned short*>(&h);
}

// async global->LDS, 16B/lane. LDS dest = wave-uniform base + lane*16.
static __device__ __forceinline__ void gld_lds16(const unsigned short* g, unsigned short* l) {
  __builtin_amdgcn_global_load_lds((const __attribute__((address_space(1))) unsigned int*)g,
                                   (__attribute__((address_space(3))) unsigned int*)l,
                                   16, 0, 0);
}

template <int N>
static __device__ __forceinline__ void waitv() {
  asm volatile("s_waitcnt vmcnt(%0)" :: "i"(N) : "memory");
}

// flat block id -> (bx, by): XCD-chunked bijective swizzle (m204), by-fastest groups of G.
template <int NX, int NY, int G>
static __device__ __forceinline__ void map_block(int orig, int& bx, int& by) {
  const int n = NX * NY;
  int xcd = orig & 7, o = orig >> 3;
  const int q = n >> 3, r = n & 7;
  int id = (xcd < r ? xcd * (q + 1) : r * (q + 1) + (xcd - r) * q) + o;
  const int gsz = NX * G;          // NY % G == 0 for all instantiations
  int grp = id / gsz;
  int rem = id - grp * gsz;
  bx = rem / G;
  by = grp * G + (rem - bx * G);
}

// ---------------- routing ----------------
__global__ void k_zero(int* cnt) { if (threadIdx.x < NEXP) cnt[threadIdx.x] = 0; }

__global__ void k_count(const int* __restrict__ dom, int* __restrict__ cnt, int* __restrict__ pos) {
  int t = blockIdx.x * 256 + threadIdx.x;
  if (t < NTOK) pos[t] = atomicAdd(&cnt[dom[t]], 1);
}

// prefix offsets + exact (expert, m-tile) work list at 128 granularity
__global__ void k_offsets(const int* __restrict__ cnt, int* __restrict__ segoff,
                          int* __restrict__ tilemap, int* __restrict__ ntiles) {
  if (threadIdx.x == 0) {
    int s = 0, k = 0;
    for (int e = 0; e < NEXP; e++) {
      segoff[e] = s;
      int c = cnt[e];
      for (int t = 0; t < ((c + 127) >> 7); t++) tilemap[k++] = (e << 16) | t;
      s += c;
    }
    segoff[NEXP] = s;
    *ntiles = k;
  }
}

__global__ void k_scatter(const int* __restrict__ dom, const int* __restrict__ pos,
                          const int* __restrict__ segoff, int* __restrict__ perm) {
  int t = blockIdx.x * 256 + threadIdx.x;
  if (t < NTOK) perm[segoff[dom[t]] + pos[t]] = t;
}

// ---------------- fp32 -> bf16 convert; writes row-major xb AND sorted xs ----------------
__global__ void k_convert_g(const float* __restrict__ src, const int* __restrict__ dom,
                            const int* __restrict__ pos, const int* __restrict__ segoff,
                            unsigned short* __restrict__ xb, unsigned short* __restrict__ xs) {
  int i = blockIdx.x * 256 + threadIdx.x;   // 8-elem chunks; DIM/8 = 128 chunks/row
  int row = i >> 7;
  int c = (i & 127) * 8;
  const float4* s = (const float4*)(src + (size_t)row * DIM + c);
  float4 a = s[0], b = s[1];
  union { unsigned short h[8]; uint4 v; } u;
  u.h[0] = f2bf(a.x); u.h[1] = f2bf(a.y); u.h[2] = f2bf(a.z); u.h[3] = f2bf(a.w);
  u.h[4] = f2bf(b.x); u.h[5] = f2bf(b.y); u.h[6] = f2bf(b.z); u.h[7] = f2bf(b.w);
  *(uint4*)(xb + (size_t)row * DIM + c) = u.v;
  int srow = segoff[dom[row]] + pos[row];
  *(uint4*)(xs + (size_t)srow * DIM + c) = u.v;
}

// ---------------- fp32 [K][N] -> bf16 [N][K] transpose-convert (weights) ----------------
__global__ void k_transpose(const float* __restrict__ src, unsigned short* __restrict__ dst,
                            int K, int N) {
  size_t moff = (size_t)blockIdx.z * K * N;
  src += moff; dst += moff;
  __shared__ float tile[64][65];
  int n0 = blockIdx.x * 64, k0 = blockIdx.y * 64;
  int t = threadIdx.x;
  int tx = t & 15, ty = t >> 4;
#pragma unroll
  for (int i = 0; i < 4; i++) {
    int kk = ty + i * 16;
    float4 v = *(const float4*)(src + (size_t)(k0 + kk) * N + n0 + tx * 4);
    tile[kk][tx * 4 + 0] = v.x; tile[kk][tx * 4 + 1] = v.y;
    tile[kk][tx * 4 + 2] = v.z; tile[kk][tx * 4 + 3] = v.w;
  }
  __syncthreads();
#pragma unroll
  for (int i = 0; i < 2; i++) {
    int chunk = t + i * 256;
    int nl = chunk >> 3;
    int k8 = (chunk & 7) * 8;
    union { unsigned short h[8]; uint4 v; } u;
#pragma unroll
    for (int j = 0; j < 8; j++) u.h[j] = f2bf(tile[k8 + j][nl]);
    *(uint4*)(dst + (size_t)(n0 + nl) * K + k0 + k8) = u.v;
  }
}

// ---------------- MFMA core: 128x128 tile, BK=32, minimum 2-phase double-buffer ----------------
// Per step: stage(next buf) -> ds_read(cur) -> 16 MFMA -> vmcnt(0) -> s_barrier.
// Stage issued BEFORE compute so HBM latency hides under ds_read+MFMA (+ other blocks' waves).
// Exactly ONE barrier per step: buf[cur^1] is only rewritten in step s+1, which starts after
// the end-of-step-s barrier; every wave's reads of buf[cur] completed before it arrived there
// (MFMA operands force lgkmcnt completion before the wave can issue past them).
// LDS swizzle (T2, both-sided per rule #21): 16B-slot ^= (row>>1)&3 via pre-swizzled global
// source (gld_lds writes linearly) + same XOR on the ds_read address (lane-constant term).
static __device__ __forceinline__ void mfma_tile(
    const unsigned short* gA0, const unsigned short* gA1,
    const unsigned short* gB0, const unsigned short* gB1,
    unsigned short (*As)[128][32], unsigned short (*Bs)[128][32],
    int tid, int K, f32x4 acc[4][4])
{
  int w = tid >> 6, lane = tid & 63;
  int p0 = w * 128 + lane;               // chunk ids p0 and p0+64 per thread
  int m16 = lane & 15;
  int kslot = (lane >> 4) ^ ((m16 >> 1) & 3);   // swizzled 16B-slot for frag reads
  int wr = (w >> 1) * 64, wc = (w & 1) * 64;

  auto stage = [&](int b) {
    unsigned short* la = &As[b][0][0] + p0 * 8;
    unsigned short* lb = &Bs[b][0][0] + p0 * 8;
    gld_lds16(gA0, la); gld_lds16(gA1, la + 512);
    gld_lds16(gB0, lb); gld_lds16(gB1, lb + 512);
    gA0 += 32; gA1 += 32; gB0 += 32; gB1 += 32;
  };

  stage(0);
  waitv<0>();
  __builtin_amdgcn_s_barrier();

  int nsteps = K >> 5;
  for (int s = 0; s < nsteps; ++s) {
    int cur = s & 1;
    if (s + 1 < nsteps) stage(cur ^ 1);      // issue next-tile loads FIRST
    bf16x8 af[4], bfr[4];
#pragma unroll
    for (int i = 0; i < 4; i++) af[i] = *(const bf16x8*)&As[cur][wr + i * 16 + m16][kslot * 8];
#pragma unroll
    for (int j = 0; j < 4; j++) bfr[j] = *(const bf16x8*)&Bs[cur][wc + j * 16 + m16][kslot * 8];
#pragma unroll
    for (int i = 0; i < 4; i++)
#pragma unroll
      for (int j = 0; j < 4; j++)
        acc[i][j] = __builtin_amdgcn_mfma_f32_16x16x32_bf16(af[i], bfr[j], acc[i][j], 0, 0, 0);
    waitv<0>();                              // this wave's stage done (drains after ~16 MFMA)
    __builtin_amdgcn_s_barrier();            // all waves staged + done reading buf[cur]
  }
}

// ---------------- pass 1: h1 = gelu(A@W1+b1) AND g = sigmoid(A@Wg+bg), K=DIM ----------------
template <bool ROUTED>
__global__ __launch_bounds__(256)
void k_gemm01(const unsigned short* __restrict__ A,
              const unsigned short* __restrict__ W1t,  // bf16 [(e,) FFN, DIM]
              const float* __restrict__ b1,
              const unsigned short* __restrict__ Wgt,  // bf16 [(e,) DIM, DIM]
              const float* __restrict__ bg,
              unsigned short* __restrict__ h1,
              float* __restrict__ g,
              const int* __restrict__ segoff,
              const int* __restrict__ tilemap,
              const int* __restrict__ ntilesp) {
  constexpr int NX = ROUTED ? NT_RT : NT_SH;
  int bx, by;
  map_block<NX, NY01, 8>((int)blockIdx.x, bx, by);

  int e = 0, seg0 = 0, cnt = NTOK, m0;
  if (ROUTED) {
    if (bx >= *ntilesp) return;
    int tm = tilemap[bx];
    e = tm >> 16;
    seg0 = segoff[e];
    cnt = segoff[e + 1] - seg0;
    m0 = (tm & 0xffff) << 7;
  } else {
    m0 = bx << 7;
  }

  const bool isW1 = by < (FFN / 128);
  const int n0 = (isW1 ? by : by - FFN / 128) << 7;
  const unsigned short* Bte = isW1 ? W1t + (size_t)e * FFN * DIM + (size_t)n0 * DIM
                                   : Wgt + (size_t)e * DIM * DIM + (size_t)n0 * DIM;
  const float* be = (isW1 ? b1 + (size_t)e * FFN : bg + (size_t)e * DIM) + n0;

  __shared__ unsigned short As[2][128][32];
  __shared__ unsigned short Bs[2][128][32];

  int tid = threadIdx.x, w = tid >> 6, lane = tid & 63;
  int p0 = w * 128 + lane;
  int r0 = p0 >> 2, r1 = r0 + 16;
  int kgx = ((p0 & 3) ^ ((p0 >> 3) & 3)) * 8;   // pre-swizzled source k-group (rule #21)

  auto arow = [&](int rl) -> size_t {
    int l = m0 + rl;
    if (ROUTED && l > cnt - 1) l = cnt - 1;   // clamp (masked at store)
    return (size_t)(seg0 + l);
  };
  const unsigned short* gA0 = A + arow(r0) * DIM + kgx;
  const unsigned short* gA1 = A + arow(r1) * DIM + kgx;
  const unsigned short* gB0 = Bte + (size_t)r0 * DIM + kgx;
  const unsigned short* gB1 = Bte + (size_t)r1 * DIM + kgx;

  f32x4 acc[4][4];
#pragma unroll
  for (int i = 0; i < 4; i++)
#pragma unroll
    for (int j = 0; j < 4; j++) acc[i][j] = (f32x4){0.f, 0.f, 0.f, 0.f};

  mfma_tile(gA0, gA1, gB0, gB1, As, Bs, tid, DIM, acc);

  // epilogue: C/D layout col = lane&15, row = (lane>>4)*4 + reg
  int m16 = lane & 15, quad = lane >> 4;
  int wr = (w >> 1) * 64, wc = (w & 1) * 64;
#pragma unroll
  for (int i = 0; i < 4; i++) {
#pragma unroll
    for (int j = 0; j < 4; j++) {
      int cn = wc + j * 16 + m16;
      int col = n0 + cn;
      float bb = be[cn];
#pragma unroll
      for (int r = 0; r < 4; r++) {
        int rl = wr + i * 16 + quad * 4 + r;
        int l = m0 + rl;
        if (ROUTED && l >= cnt) continue;
        float z = acc[i][j][r] + bb;
        size_t row = (size_t)(seg0 + l);
        if (isW1) {
          // tanh-form gelu: |err| <= 3e-3, below bf16 h1 quantization (validated r2)
          float u = 0.79788456f * z * (1.0f + 0.044715f * z * z);
          float o = z / (1.0f + __expf(-2.0f * u));
          h1[row * (size_t)FFN + col] = f2bf(o);
        } else {
          g[row * (size_t)DIM + col] = 1.0f / (1.0f + __expf(-z));
        }
      }
    }
  }
}

// ---------------- pass 2: h = A@W2+b2+x; out (=/+=) g*h+(1-g)*x, K=FFN ----------------
template <bool ROUTED>
__global__ __launch_bounds__(256)
void k_gemm2(const unsigned short* __restrict__ A,     // h1 bf16 (sorted rows if ROUTED)
             const unsigned short* __restrict__ W2t,   // bf16 [(e,) DIM, FFN]
             const float* __restrict__ b2,
             const float* __restrict__ g,
             const float* __restrict__ xres,
             float* __restrict__ out,
             const int* __restrict__ perm,
             const int* __restrict__ segoff,
             const int* __restrict__ tilemap,
             const int* __restrict__ ntilesp) {
  constexpr int NX = ROUTED ? NT_RT : NT_SH;
  int bx, by;
  map_block<NX, NY2, 2>((int)blockIdx.x, bx, by);

  int e = 0, seg0 = 0, cnt = NTOK, m0;
  if (ROUTED) {
    if (bx >= *ntilesp) return;
    int tm = tilemap[bx];
    e = tm >> 16;
    seg0 = segoff[e];
    cnt = segoff[e + 1] - seg0;
    m0 = (tm & 0xffff) << 7;
  } else {
    m0 = bx << 7;
  }
  const int n0 = by << 7;
  const unsigned short* Bte = W2t + (size_t)e * DIM * FFN + (size_t)n0 * FFN;
  const float* be = b2 + (size_t)e * DIM + n0;

  __shared__ unsigned short As[2][128][32];
  __shared__ unsigned short Bs[2][128][32];

  int tid = threadIdx.x, w = tid >> 6, lane = tid & 63;
  int p0 = w * 128 + lane;
  int r0 = p0 >> 2, r1 = r0 + 16;
  int kgx = ((p0 & 3) ^ ((p0 >> 3) & 3)) * 8;

  auto arow = [&](int rl) -> size_t {
    int l = m0 + rl;
    if (ROUTED && l > cnt - 1) l = cnt - 1;
    return (size_t)(seg0 + l);
  };
  const unsigned short* gA0 = A + arow(r0) * FFN + kgx;
  const unsigned short* gA1 = A + arow(r1) * FFN + kgx;
  const unsigned short* gB0 = Bte + (size_t)r0 * FFN + kgx;
  const unsigned short* gB1 = Bte + (size_t)r1 * FFN + kgx;

  f32x4 acc[4][4];
#pragma unroll
  for (int i = 0; i < 4; i++)
#pragma unroll
    for (int j = 0; j < 4; j++) acc[i][j] = (f32x4){0.f, 0.f, 0.f, 0.f};

  mfma_tile(gA0, gA1, gB0, gB1, As, Bs, tid, FFN, acc);

  int m16 = lane & 15, quad = lane >> 4;
  int wr = (w >> 1) * 64, wc = (w & 1) * 64;
#pragma unroll
  for (int i = 0; i < 4; i++) {
#pragma unroll
    for (int j = 0; j < 4; j++) {
      int cn = wc + j * 16 + m16;
      int col = n0 + cn;
      float bb = be[cn];
#pragma unroll
      for (int r = 0; r < 4; r++) {
        int rl = wr + i * 16 + quad * 4 + r;
        int l = m0 + rl;
        if (ROUTED && l >= cnt) continue;
        int lidx = seg0 + l;
        int grow = ROUTED ? perm[lidx] : l;      // global token row
        float xv = xres[(size_t)grow * DIM + col];
        float gv = g[(size_t)lidx * DIM + col];
        float h = acc[i][j][r] + bb + xv;
        float o = gv * h + (1.0f - gv) * xv;
        float* po = &out[(size_t)grow * DIM + col];
        if (ROUTED) *po += o;   // unique rows per token: no atomics needed
        else        *po = o;
      }
    }
  }
}

extern "C" void kernel_launch(void* const* d_in, const int* in_sizes, int n_in,
                              void* d_out, int out_size, void* d_ws, size_t ws_size,
                              hipStream_t stream) {
  (void)in_sizes; (void)n_in; (void)out_size; (void)ws_size;
  const float* x   = (const float*)d_in[0];
  const int*   dom = (const int*)d_in[1];
  const float* sW1 = (const float*)d_in[2];
  const float* sb1 = (const float*)d_in[3];
  const float* sW2 = (const float*)d_in[4];
  const float* sb2 = (const float*)d_in[5];
  const float* sWg = (const float*)d_in[6];
  const float* sbg = (const float*)d_in[7];
  const float* dW1 = (const float*)d_in[8];
  const float* db1 = (const float*)d_in[9];
  const float* dW2 = (const float*)d_in[10];
  const float* db2 = (const float*)d_in[11];
  const float* dWg = (const float*)d_in[12];
  const float* dbg = (const float*)d_in[13];
  float* out = (float*)d_out;

  char* p = (char*)d_ws;
  auto take = [&](size_t b) { char* r = p; p += (b + 255) & ~(size_t)255; return r; };
  int* cnt     = (int*)take(NEXP * 4);
  int* segoff  = (int*)take((NEXP + 1) * 4);
  int* tilemap = (int*)take(128 * 4);
  int* ntiles  = (int*)take(4);
  int* pos     = (int*)take((size_t)NTOK * 4);
  int* perm    = (int*)take((size_t)NTOK * 4);
  unsigned short* xb   = (unsigned short*)take((size_t)NTOK * DIM * 2);
  unsigned short* xs   = (unsigned short*)take((size_t)NTOK * DIM * 2);   // sorted x
  unsigned short* h1   = (unsigned short*)take((size_t)NTOK * FFN * 2);   // reused shared->routed
  float*          g    = (float*)take((size_t)NTOK * DIM * 4);            // reused shared->routed
  unsigned short* sW1t = (unsigned short*)take((size_t)DIM * FFN * 2);
  unsigned short* sW2t = (unsigned short*)take((size_t)FFN * DIM * 2);
  unsigned short* sWgt = (unsigned short*)take((size_t)DIM * DIM * 2);
  unsigned short* dW1t = (unsigned short*)take((size_t)NEXP * DIM * FFN * 2);
  unsigned short* dW2t = (unsigned short*)take((size_t)NEXP * FFN * DIM * 2);
  unsigned short* dWgt = (unsigned short*)take((size_t)NEXP * DIM * DIM * 2);

  // routing (+ exact routed tile list)
  k_zero<<<1, 64, 0, stream>>>(cnt);
  k_count<<<NTOK / 256, 256, 0, stream>>>(dom, cnt, pos);
  k_offsets<<<1, 1, 0, stream>>>(cnt, segoff, tilemap, ntiles);
  k_scatter<<<NTOK / 256, 256, 0, stream>>>(dom, pos, segoff, perm);

  // convert x (writes row-major xb + sorted xs in one pass); transpose-convert weights
  k_convert_g<<<(NTOK * DIM / 8) / 256, 256, 0, stream>>>(x, dom, pos, segoff, xb, xs);
  k_transpose<<<dim3(FFN / 64, DIM / 64, 1),    256, 0, stream>>>(sW1, sW1t, DIM, FFN);
  k_transpose<<<dim3(DIM / 64, FFN / 64, 1),    256, 0, stream>>>(sW2, sW2t, FFN, DIM);
  k_transpose<<<dim3(DIM / 64, DIM / 64, 1),    256, 0, stream>>>(sWg, sWgt, DIM, DIM);
  k_transpose<<<dim3(FFN / 64, DIM / 64, NEXP), 256, 0, stream>>>(dW1, dW1t, DIM, FFN);
  k_transpose<<<dim3(DIM / 64, FFN / 64, NEXP), 256, 0, stream>>>(dW2, dW2t, FFN, DIM);
  k_transpose<<<dim3(DIM / 64, DIM / 64, NEXP), 256, 0, stream>>>(dWg, dWgt, DIM, DIM);

  // shared expert pass (h1+g in one dispatch, then combine; writes every out element)
  k_gemm01<false><<<NT_SH * NY01, 256, 0, stream>>>(
      xb, sW1t, sb1, sWgt, sbg, h1, g, nullptr, nullptr, nullptr);
  k_gemm2<false><<<NT_SH * NY2, 256, 0, stream>>>(
      h1, sW2t, sb2, g, x, out, nullptr, nullptr, nullptr, nullptr);

  // routed expert pass (exact tile list; accumulates into out); reuses h1/g at sorted rows
  k_gemm01<true><<<NT_RT * NY01, 256, 0, stream>>>(
      xs, dW1t, db1, dWgt, dbg, h1, g, segoff, tilemap, ntiles);
  k_gemm2<true><<<NT_RT * NY2, 256, 0, stream>>>(
      h1, dW2t, db2, g, x, out, perm, segoff, tilemap, ntiles);
}